// Round 2
// baseline (281.813 us; speedup 1.0000x reference)
//
#include <hip/hip_runtime.h>

// ---------------------------------------------------------------------------
// SelfAttentionBlock: B=4, N=2048, D=1024.
//   QKV = X @ Wqkv^T                   (8192x1024)@(3072x1024)^T   [256² 8-phase]
//   E_b = exp(Q_b @ K_b^T * 0.125)     bf16 + row sums L (atomic)  [256² 8-phase]
//   V''_b = Wout @ V_b^T               (1024x2048) per batch       [256² 8-phase, fused]
//   out_b = (E_b @ V''_b^T) / L + b    fp32                        [128² proven core]
// R9: 256²/BK=64/8-wave 8-phase schedule with counted vmcnt(4) (T3+T4) and
// setprio (T5) for the two large-grid dispatches. LDS k-half-major
// [2][256][32] double-buffered (128 KiB dynamic), XOR swizzle q^((r>>1)&3)
// (bank-optimal for 64B row stride), swizzle realized on the GLOBAL source
// so global_load_lds dst stays wave-linear. Staging of tile t+1 spread over
// tile t's 4 phases (order Ak0,Bk0,Ak1,Bk1); vmcnt(4) twice per K-tile
// guarantees exactly the half-tiles the next 2 phases read.
// ---------------------------------------------------------------------------

typedef __bf16 bf16;
typedef __attribute__((ext_vector_type(8))) __bf16 bf16x8;
typedef __attribute__((ext_vector_type(4))) __bf16 bf16x4;
typedef __attribute__((ext_vector_type(16))) float f32x16;

#define BATCH 4
#define NTOK  2048
#define DIM   1024
#define MROWS (BATCH * NTOK)   // 8192
#define QKVC  (3 * DIM)        // 3072
#define KT256 16               // K=1024 / BK=64 for all three big GEMMs

__device__ __forceinline__ void async16(const bf16* g, bf16* l) {
  __builtin_amdgcn_global_load_lds(
      (const __attribute__((address_space(1))) void*)g,
      (__attribute__((address_space(3))) void*)l, 16, 0, 0);
}

// ---------------------------------------------------------------------------
// prep: three fp32->bf16 converts + L zero
// ---------------------------------------------------------------------------
__device__ __forceinline__ void cvt4(const float* in, bf16* out, int i4) {
  float4 f = *(const float4*)(in + i4 * 4);
  bf16x4 o;
  o.x = (bf16)f.x; o.y = (bf16)f.y; o.z = (bf16)f.z; o.w = (bf16)f.w;
  *(bf16x4*)(out + i4 * 4) = o;
}

__global__ void prep(const float* __restrict__ x, const float* __restrict__ wqkv,
                     const float* __restrict__ wout,
                     bf16* __restrict__ Xbf, bf16* __restrict__ Wqkvb,
                     bf16* __restrict__ Woutb, float* __restrict__ L) {
  const int nx = MROWS * DIM / 4, nq = QKVC * DIM / 4, nw = DIM * DIM / 4;
  const int nl = BATCH * NTOK / 4;
  int i = blockIdx.x * blockDim.x + threadIdx.x;
  if (i < nx) cvt4(x, Xbf, i);
  else if (i < nx + nq) cvt4(wqkv, Wqkvb, i - nx);
  else if (i < nx + nq + nw) cvt4(wout, Woutb, i - nx - nq);
  else if (i < nx + nq + nw + nl) {
    float4 z = {0.f, 0.f, 0.f, 0.f};
    *(float4*)(L + (i - nx - nq - nw) * 4) = z;
  }
}

// ===========================================================================
// 256x256 8-phase GEMM core (T2+T3+T4+T5). C[i][j] = sum_k A[i][k]*B[j][k].
// 8 waves as 2(M)x4(N); per-wave out 128x64 = 4x2 of 32x32; BK=64.
// LDS per tile: A[2 khalf][256 r][32 c] = 32 KB (same B), double buffered =
// 128 KB. Physical chunk q (8 elems) of row r, k-half h holds logical chunk
// q ^ ((r>>1)&3). Stage shot = 128 rows x 32 cols = 8 KB = 512 thr x 16 B,
// LDS dst linear in tid; swizzle applied to global source col.
// Per phase p (k-chunk p of current tile): 6 ds_read_b128 + stage half-tile p
// of tile t+1 (2 async16) + [vmcnt(4) if p odd] + barrier + lgkmcnt(0) +
// setprio(1) + 8 MFMA + setprio(0) + barrier.
// vmcnt ledger (2 loads/half-tile, issue order Ak0,Bk0,Ak1,Bk1):
//   entering t.p0: outstanding<=4={Ak1(t),Bk1(t)}, Ak0/Bk0(t) landed.
//   t.p1 vmcnt(4) -> Ak1(t),Bk1(t) landed (needed by p2,p3).
//   t.p3 vmcnt(4) -> Ak0(t+1),Bk0(t+1) landed (needed by t+1.p0,p1).
// Last tile: no stage, vmcnt(0) at p1 (drains Ak1,Bk1 of last tile).
// ===========================================================================

template <bool MORE>
__device__ __forceinline__ void g256_iter(
    const bf16* Ac, const bf16* Bc, bf16* An, bf16* Bn, int kn,
    const bf16* gA0, const bf16* gA1, const bf16* gB0, const bf16* gB1,
    int dst, const int rA[4], const int rB[2], int f, int half,
    f32x16 acc[4][2]) {
#pragma unroll
  for (int p = 0; p < 4; ++p) {
    const int c = (p & 1) * 2 + half;
    const int co = ((c ^ f) & 3) * 8 + (p >> 1) * 8192;
    bf16x8 av[4], bv[2];
#pragma unroll
    for (int ti = 0; ti < 4; ++ti) av[ti] = *(const bf16x8*)&Ac[rA[ti] + co];
#pragma unroll
    for (int tj = 0; tj < 2; ++tj) bv[tj] = *(const bf16x8*)&Bc[rB[tj] + co];
    if (MORE) {
      if (p == 0)      { async16(gA0 + kn,      An + dst);         async16(gA1 + kn,      An + 4096  + dst); }
      else if (p == 1) { async16(gB0 + kn,      Bn + dst);         async16(gB1 + kn,      Bn + 4096  + dst); }
      else if (p == 2) { async16(gA0 + kn + 32, An + 8192 + dst);  async16(gA1 + kn + 32, An + 12288 + dst); }
      else             { async16(gB0 + kn + 32, Bn + 8192 + dst);  async16(gB1 + kn + 32, Bn + 12288 + dst); }
    }
    if (p & 1) {
      if (MORE) asm volatile("s_waitcnt vmcnt(4)" ::: "memory");
      else      asm volatile("s_waitcnt vmcnt(0)" ::: "memory");
    }
    __builtin_amdgcn_sched_barrier(0);
    __builtin_amdgcn_s_barrier();
    __builtin_amdgcn_sched_barrier(0);
    asm volatile("s_waitcnt lgkmcnt(0)" ::: "memory");
    __builtin_amdgcn_sched_barrier(0);
    __builtin_amdgcn_s_setprio(1);
#pragma unroll
    for (int ti = 0; ti < 4; ++ti)
#pragma unroll
      for (int tj = 0; tj < 2; ++tj)
        acc[ti][tj] = __builtin_amdgcn_mfma_f32_32x32x16_bf16(
            av[ti], bv[tj], acc[ti][tj], 0, 0, 0);
    __builtin_amdgcn_s_setprio(0);
    __builtin_amdgcn_sched_barrier(0);
    __builtin_amdgcn_s_barrier();
    __builtin_amdgcn_sched_barrier(0);
  }
}

__device__ __forceinline__ void gemm256(const bf16* __restrict__ A,
                                        const bf16* __restrict__ Bm,
                                        int lda, int ldb, long rowA, long rowB,
                                        bf16* sm, int l31, int half, int wr, int wc,
                                        f32x16 acc[4][2]) {
  const int tid = threadIdx.x;
  const int sr = tid >> 2, sq = tid & 3;
  const int sf = (sr >> 1) & 3;
  const int scol = (sq ^ sf) * 8;          // swizzled source chunk within k-half
  const bf16* gA0 = A  + (rowA + sr) * (long)lda + scol;
  const bf16* gA1 = A  + (rowA + sr + 128) * (long)lda + scol;
  const bf16* gB0 = Bm + (rowB + sr) * (long)ldb + scol;
  const bf16* gB1 = Bm + (rowB + sr + 128) * (long)ldb + scol;

  bf16* Ab0 = sm;             // tile buf 0: A
  bf16* Ab1 = sm + 16384;     // tile buf 1: A
  bf16* Bb0 = sm + 32768;
  bf16* Bb1 = sm + 49152;
  const int dst = tid * 8;

  int rA[4], rB[2];
#pragma unroll
  for (int ti = 0; ti < 4; ++ti) rA[ti] = (wr * 128 + ti * 32 + l31) * 32;
#pragma unroll
  for (int tj = 0; tj < 2; ++tj) rB[tj] = (wc * 64 + tj * 32 + l31) * 32;
  const int f = (l31 >> 1) & 3;

  // prologue: stage tile 0 into buf0 (order Ak0, Bk0, Ak1, Bk1)
  async16(gA0, Ab0 + dst);            async16(gA1, Ab0 + 4096 + dst);
  async16(gB0, Bb0 + dst);            async16(gB1, Bb0 + 4096 + dst);
  async16(gA0 + 32, Ab0 + 8192 + dst); async16(gA1 + 32, Ab0 + 12288 + dst);
  async16(gB0 + 32, Bb0 + 8192 + dst); async16(gB1 + 32, Bb0 + 12288 + dst);
  asm volatile("s_waitcnt vmcnt(4)" ::: "memory");
  __builtin_amdgcn_sched_barrier(0);
  __builtin_amdgcn_s_barrier();
  __builtin_amdgcn_sched_barrier(0);

#pragma unroll 1
  for (int t2 = 0; t2 < 7; ++t2) {
    g256_iter<true >(Ab0, Bb0, Ab1, Bb1, (2 * t2 + 1) * 64, gA0, gA1, gB0, gB1, dst, rA, rB, f, half, acc);
    g256_iter<true >(Ab1, Bb1, Ab0, Bb0, (2 * t2 + 2) * 64, gA0, gA1, gB0, gB1, dst, rA, rB, f, half, acc);
  }
  g256_iter<true >(Ab0, Bb0, Ab1, Bb1, 15 * 64, gA0, gA1, gB0, gB1, dst, rA, rB, f, half, acc);
  g256_iter<false>(Ab1, Bb1, Ab0, Bb0, 0,       gA0, gA1, gB0, gB1, dst, rA, rB, f, half, acc);
}

// ---- QKV = X @ Wqkv^T, 256² tiles, bf16 out --------------------------------
__launch_bounds__(512, 2)
__global__ void gemm256_qkv(const bf16* __restrict__ Xb, const bf16* __restrict__ Wq,
                            bf16* __restrict__ QKV) {
  extern __shared__ bf16 sm[];
  const int tid = threadIdx.x, wave = tid >> 6, lane = tid & 63;
  const int wr = wave >> 2, wc = wave & 3, l31 = lane & 31, half = lane >> 5;
  const long rowA = (long)blockIdx.y * 256;
  const long rowB = (long)blockIdx.x * 256;
  f32x16 acc[4][2] = {};
  gemm256(Xb, Wq, DIM, DIM, rowA, rowB, sm, l31, half, wr, wc, acc);
#pragma unroll
  for (int ti = 0; ti < 4; ++ti)
#pragma unroll
    for (int tj = 0; tj < 2; ++tj) {
      const long col = rowB + wc * 64 + tj * 32 + l31;
#pragma unroll
      for (int r = 0; r < 16; ++r) {
        const long row = rowA + wr * 128 + ti * 32 + (r & 3) + 8 * (r >> 2) + 4 * half;
        QKV[row * (long)QKVC + col] = (bf16)acc[ti][tj][r];
      }
    }
}

// ---- fused: z<4 -> E_b = exp(QK^T/8)+L ; z>=4 -> V''_b = Wout @ V_b^T ------
__launch_bounds__(512, 2)
__global__ void gemm256_sv(const bf16* __restrict__ QKV, const bf16* __restrict__ Wout,
                           bf16* __restrict__ E, bf16* __restrict__ Vpp,
                           float* __restrict__ Lroot) {
  extern __shared__ bf16 sm[];
  const int tid = threadIdx.x, wave = tid >> 6, lane = tid & 63;
  const int wr = wave >> 2, wc = wave & 3, l31 = lane & 31, half = lane >> 5;
  const int z = blockIdx.z;
  if (z < 4) {
    const bf16* A  = QKV + (long)z * NTOK * QKVC;
    const bf16* Bm = A + DIM;
    const long rowA = (long)blockIdx.y * 256;
    const long rowB = (long)blockIdx.x * 256;
    f32x16 acc[4][2] = {};
    gemm256(A, Bm, QKVC, QKVC, rowA, rowB, sm, l31, half, wr, wc, acc);

    bf16* C = E + (long)z * NTOK * NTOK;
    float* L = Lroot + (long)z * NTOK;
#pragma unroll
    for (int ti = 0; ti < 4; ++ti) {
#pragma unroll
      for (int r = 0; r < 16; ++r) {
        const long row = rowA + wr * 128 + ti * 32 + (r & 3) + 8 * (r >> 2) + 4 * half;
        float psum = 0.f;
#pragma unroll
        for (int tj = 0; tj < 2; ++tj) {
          const long col = rowB + wc * 64 + tj * 32 + l31;
          float e = __expf(acc[ti][tj][r] * 0.125f);
          bf16 eb = (bf16)e;
          C[row * (long)NTOK + col] = eb;
          psum += (float)eb;   // sum what downstream consumes
        }
#pragma unroll
        for (int off = 16; off >= 1; off >>= 1) psum += __shfl_xor(psum, off, 64);
        if (l31 == 0) atomicAdd(&L[row], psum);
      }
    }
  } else {
    if (blockIdx.y >= 4) return;   // V'' has 1024 rows = 4 row-tiles
    const int b = z - 4;
    const bf16* Bm = QKV + (long)b * NTOK * QKVC + 2 * DIM;
    const long rowA = (long)blockIdx.y * 256;
    const long rowB = (long)blockIdx.x * 256;
    f32x16 acc[4][2] = {};
    gemm256(Wout, Bm, DIM, QKVC, rowA, rowB, sm, l31, half, wr, wc, acc);

    bf16* C = Vpp + (long)b * DIM * NTOK;
#pragma unroll
    for (int ti = 0; ti < 4; ++ti)
#pragma unroll
      for (int tj = 0; tj < 2; ++tj) {
        const long col = rowB + wc * 64 + tj * 32 + l31;
#pragma unroll
        for (int r = 0; r < 16; ++r) {
          const long row = rowA + wr * 128 + ti * 32 + (r & 3) + 8 * (r >> 2) + 4 * half;
          C[row * (long)NTOK + col] = (bf16)acc[ti][tj][r];
        }
      }
  }
}

// ===========================================================================
// 128² proven core (kept for out-GEMM: grid 512 blocks; 256² would idle half
// the GPU at 128 blocks).
// ===========================================================================
struct GemmCore {
  const bf16 *ga[4], *gb[4];
  int sIdx[4];
  int wm, wn, l31, half;
};

__device__ __forceinline__ GemmCore gemm_setup(const bf16* A, const bf16* Bm,
                                               int lda, int ldb,
                                               long rowA, long rowB) {
  GemmCore g;
  const int tid = threadIdx.x;
  const int wave = tid >> 6, lane = tid & 63;
  g.wm = (wave >> 1) << 6;
  g.wn = (wave & 1) << 6;
  g.l31 = lane & 31;
  g.half = lane >> 5;
  const int srow = tid >> 3;               // 0..31
  const int sc   = tid & 7;                // physical slot
  const int scol = (sc ^ (srow & 7)) << 3; // swizzled global chunk * 8
#pragma unroll
  for (int seg = 0; seg < 4; ++seg) {
    g.ga[seg] = A  + (rowA + srow + 32 * seg) * (long)lda + scol;
    g.gb[seg] = Bm + (rowB + srow + 32 * seg) * (long)ldb + scol;
    g.sIdx[seg] = (srow + 32 * seg) * 64 + sc * 8;
  }
  return g;
}

__device__ __forceinline__ void gemm_kloop(const GemmCore& g, int K,
                                           bf16* As, bf16* Bs, f32x16 acc[2][2]) {
  const int sw = g.l31 & 7;
  for (int kt = 0; kt < K; kt += 64) {
#pragma unroll
    for (int seg = 0; seg < 4; ++seg) {
      async16(g.ga[seg] + kt, As + g.sIdx[seg]);
      async16(g.gb[seg] + kt, Bs + g.sIdx[seg]);
    }
    __syncthreads();

    bf16x8 af[2][4], bfm[2][4];
#pragma unroll
    for (int ti = 0; ti < 2; ++ti)
#pragma unroll
      for (int s = 0; s < 4; ++s)
        af[ti][s] = *(const bf16x8*)&As[(g.wm + ti * 32 + g.l31) * 64 + ((s * 2 + g.half) ^ sw) * 8];
#pragma unroll
    for (int tj = 0; tj < 2; ++tj)
#pragma unroll
      for (int s = 0; s < 4; ++s)
        bfm[tj][s] = *(const bf16x8*)&Bs[(g.wn + tj * 32 + g.l31) * 64 + ((s * 2 + g.half) ^ sw) * 8];

#pragma unroll
    for (int s = 0; s < 4; ++s)
#pragma unroll
      for (int ti = 0; ti < 2; ++ti)
#pragma unroll
        for (int tj = 0; tj < 2; ++tj)
          acc[ti][tj] = __builtin_amdgcn_mfma_f32_32x32x16_bf16(
              af[ti][s], bfm[tj][s], acc[ti][tj], 0, 0, 0);

    __syncthreads();
  }
}

// MODE 2: store fp32 acc/L[row] + bias[col].
template <int MODE>
__launch_bounds__(256)
__global__ void gemm_bt(const bf16* __restrict__ Aroot, const bf16* __restrict__ Broot,
                        void* __restrict__ Croot, const float* __restrict__ bias,
                        const float* __restrict__ Lroot,
                        int K, int lda, int ldb, int ldc,
                        long strideA, long strideB, long strideC) {
  const bf16* A  = Aroot + (long)blockIdx.z * strideA;
  const bf16* Bm = Broot + (long)blockIdx.z * strideB;
  __shared__ alignas(16) bf16 As[128 * 64];
  __shared__ alignas(16) bf16 Bs[128 * 64];

  const long rowA = (long)blockIdx.y * 128;
  const long rowB = (long)blockIdx.x * 128;
  GemmCore g = gemm_setup(A, Bm, lda, ldb, rowA, rowB);

  f32x16 acc[2][2] = {};
  gemm_kloop(g, K, As, Bs, acc);

  if constexpr (MODE == 0) {
    bf16* C = (bf16*)Croot + (long)blockIdx.z * strideC;
#pragma unroll
    for (int ti = 0; ti < 2; ++ti)
#pragma unroll
      for (int tj = 0; tj < 2; ++tj) {
        const long col = rowB + g.wn + tj * 32 + g.l31;
#pragma unroll
        for (int r = 0; r < 16; ++r) {
          const long row = rowA + g.wm + ti * 32 + (r & 3) + 8 * (r >> 2) + 4 * g.half;
          C[row * (long)ldc + col] = (bf16)acc[ti][tj][r];
        }
      }
  } else {
    float* C = (float*)Croot + (long)blockIdx.z * strideC;
    const float* L = Lroot + (long)blockIdx.z * NTOK;
#pragma unroll
    for (int ti = 0; ti < 2; ++ti) {
#pragma unroll
      for (int r = 0; r < 16; ++r) {
        const long row = rowA + g.wm + ti * 32 + (r & 3) + 8 * (r >> 2) + 4 * g.half;
        const float inv = 1.0f / L[row];
#pragma unroll
        for (int tj = 0; tj < 2; ++tj) {
          const long col = rowB + g.wn + tj * 32 + g.l31;
          C[row * (long)ldc + col] = acc[ti][tj][r] * inv + bias[col];
        }
      }
    }
  }
}

// ---------------------------------------------------------------------------
extern "C" void kernel_launch(void* const* d_in, const int* in_sizes, int n_in,
                              void* d_out, int out_size, void* d_ws, size_t ws_size,
                              hipStream_t stream) {
  const float* x      = (const float*)d_in[0];   // (4,2048,1024)
  const float* w_qkv  = (const float*)d_in[1];   // (3072,1024)
  const float* w_out  = (const float*)d_in[2];   // (1024,1024)
  const float* b_out  = (const float*)d_in[3];   // (1024,)
  float* out = (float*)d_out;                    // (4,2048,1024) fp32

  // workspace layout (bytes) — total ~120 MiB
  char* w = (char*)d_ws;
  bf16*  Xbf   = (bf16*)(w);                          // 8192*1024*2   = 16 MiB
  bf16*  Wqkvb = (bf16*)(w + 16777216);               // 3072*1024*2   =  6 MiB
  bf16*  Woutb = (bf16*)(w + 23068672);               // 1024*1024*2   =  2 MiB
  bf16*  QKV   = (bf16*)(w + 25165824);               // 8192*3072*2   = 48 MiB
  bf16*  E     = (bf16*)(w + 75497472);               // 4*2048*2048*2 = 32 MiB
  bf16*  Vpp   = (bf16*)(w + 109051904);              // 4*1024*2048*2 = 16 MiB
  float* L     = (float*)(w + 125829120);             // 4*2048*4      = 32 KiB

  // 1) one prep dispatch: converts + L zero
  {
    const int n4 = MROWS * DIM / 4 + QKVC * DIM / 4 + DIM * DIM / 4 + BATCH * NTOK / 4;
    prep<<<(n4 + 255) / 256, 256, 0, stream>>>(x, w_qkv, w_out, Xbf, Wqkvb, Woutb, L);
  }

  // 2) QKV = X @ Wqkv^T -> bf16 (8192 x 3072), 256² 8-phase, 384 blocks
  gemm256_qkv<<<dim3(QKVC / 256, MROWS / 256, 1), 512, 131072, stream>>>(
      Xbf, Wqkvb, QKV);

  // 3) fused: E_b = exp(Q_b@K_b^T/8) + L row-sums AND V''_b = Wout @ V_b^T
  //    256² 8-phase; z<4: 8x8 E-tiles; z>=4: 8x4 V''-tiles (y>=4 idle)
  gemm256_sv<<<dim3(NTOK / 256, NTOK / 256, 2 * BATCH), 512, 131072, stream>>>(
      QKV, Woutb, E, Vpp, L);

  // 4) out_b = (E_b @ V''_b^T) / L + b_out -> fp32 (2048 x 1024 per batch)
  gemm_bt<2><<<dim3(DIM / 128, NTOK / 128, BATCH), 256, 0, stream>>>(
      E, Vpp, out, b_out, L, NTOK, NTOK, NTOK, DIM,
      (long)NTOK * NTOK, (long)DIM * NTOK, (long)NTOK * DIM);
}

// Round 3
// 267.276 us; speedup vs baseline: 1.0544x; 1.0544x over previous
//
#include <hip/hip_runtime.h>

// ---------------------------------------------------------------------------
// SelfAttentionBlock: B=4, N=2048, D=1024. Single-head attention, head dim 1024.
//   QKV = X @ Wqkv^T                   (8192x1024)@(3072x1024)^T
//   E_b = exp(Q_b @ K_b^T * 0.125)     bf16, fused in S-GEMM epilogue,
//                                      row sums L accumulated atomically
//   V''_b = Wout @ V_b^T               (1024x2048) per batch
//   out_b = (E_b @ V''_b^T) / L + b    fp32  ( == softmax(S)@V@Wout^T + b )
// R10: 2-phase double-buffered K-loop (T3 minimum recipe) on the proven 128²
// core: stage(t+1)->other buf BEFORE compute(t), ONE vmcnt(0)+lgkmcnt(0)+
// barrier per K-tile (was: drain immediately after stage issue = zero flight
// time, 2 barriers/tile). LDS 64 KiB/block -> still 2 blocks/CU.
// R9 (256² 8-phase port) REGRESSED (25% MfmaUtil, sched_barrier over-pinning
// + 1.5-round work quantization) — reverted.
// ---------------------------------------------------------------------------

typedef __bf16 bf16;
typedef __attribute__((ext_vector_type(8))) __bf16 bf16x8;
typedef __attribute__((ext_vector_type(4))) __bf16 bf16x4;
typedef __attribute__((ext_vector_type(16))) float f32x16;

#define BATCH 4
#define NTOK  2048
#define DIM   1024
#define MROWS (BATCH * NTOK)   // 8192
#define QKVC  (3 * DIM)        // 3072

__device__ __forceinline__ void async16(const bf16* g, bf16* l) {
  __builtin_amdgcn_global_load_lds(
      (const __attribute__((address_space(1))) void*)g,
      (__attribute__((address_space(3))) void*)l, 16, 0, 0);
}

// ---------------------------------------------------------------------------
// one prep kernel: three fp32->bf16 converts + L zero
// ---------------------------------------------------------------------------
__device__ __forceinline__ void cvt4(const float* in, bf16* out, int i4) {
  float4 f = *(const float4*)(in + i4 * 4);
  bf16x4 o;
  o.x = (bf16)f.x; o.y = (bf16)f.y; o.z = (bf16)f.z; o.w = (bf16)f.w;
  *(bf16x4*)(out + i4 * 4) = o;
}

__global__ void prep(const float* __restrict__ x, const float* __restrict__ wqkv,
                     const float* __restrict__ wout,
                     bf16* __restrict__ Xbf, bf16* __restrict__ Wqkvb,
                     bf16* __restrict__ Woutb, float* __restrict__ L) {
  const int nx = MROWS * DIM / 4, nq = QKVC * DIM / 4, nw = DIM * DIM / 4;
  const int nl = BATCH * NTOK / 4;
  int i = blockIdx.x * blockDim.x + threadIdx.x;
  if (i < nx) cvt4(x, Xbf, i);
  else if (i < nx + nq) cvt4(wqkv, Wqkvb, i - nx);
  else if (i < nx + nq + nw) cvt4(wout, Woutb, i - nx - nq);
  else if (i < nx + nq + nw + nl) {
    float4 z = {0.f, 0.f, 0.f, 0.f};
    *(float4*)(L + (i - nx - nq - nw) * 4) = z;
  }
}

// ---------------------------------------------------------------------------
// GEMM core. C[i][j] = sum_k A[i][k] * B[j][k] (B^T pattern). BK=64.
// 32x32x16 MFMA, 4 waves 2x2, wave 64x64 = 2x2 of 32x32.
// A-frag: A[m=lane&31][k=8*(lane>>5)+e]. C/D: col=lane&31,
// row=(reg&3)+8*(reg>>2)+4*(lane>>5).
// LDS tile [128 rows][64 k], 128B rows = 8 chunks; slot c of row r holds
// global chunk c^(r&7). Staging: tid -> row=tid>>3 (+32*seg), slot=tid&7;
// 8 lanes/row cover one contiguous 128B global segment -> coalesced, and
// LDS dst stays linear tid*16 (wave-uniform base + lane*16).
// ---------------------------------------------------------------------------
struct GemmCore {
  const bf16 *ga[4], *gb[4];
  int sIdx[4];
  int wm, wn, l31, half;
};

__device__ __forceinline__ GemmCore gemm_setup(const bf16* A, const bf16* Bm,
                                               int lda, int ldb,
                                               long rowA, long rowB) {
  GemmCore g;
  const int tid = threadIdx.x;
  const int wave = tid >> 6, lane = tid & 63;
  g.wm = (wave >> 1) << 6;
  g.wn = (wave & 1) << 6;
  g.l31 = lane & 31;
  g.half = lane >> 5;
  const int srow = tid >> 3;               // 0..31
  const int sc   = tid & 7;                // physical slot
  const int scol = (sc ^ (srow & 7)) << 3; // swizzled global chunk * 8
#pragma unroll
  for (int seg = 0; seg < 4; ++seg) {
    g.ga[seg] = A  + (rowA + srow + 32 * seg) * (long)lda + scol;
    g.gb[seg] = Bm + (rowB + srow + 32 * seg) * (long)ldb + scol;
    g.sIdx[seg] = (srow + 32 * seg) * 64 + sc * 8;
  }
  return g;
}

__device__ __forceinline__ void stage_tile(const GemmCore& g, int kt,
                                           bf16* As, bf16* Bs) {
#pragma unroll
  for (int seg = 0; seg < 4; ++seg) {
    async16(g.ga[seg] + kt, As + g.sIdx[seg]);
    async16(g.gb[seg] + kt, Bs + g.sIdx[seg]);
  }
}

__device__ __forceinline__ void compute_tile(const GemmCore& g,
                                             const bf16* As, const bf16* Bs,
                                             f32x16 acc[2][2]) {
  const int sw = g.l31 & 7;
  bf16x8 af[2][4], bfm[2][4];
#pragma unroll
  for (int ti = 0; ti < 2; ++ti)
#pragma unroll
    for (int s = 0; s < 4; ++s)
      af[ti][s] = *(const bf16x8*)&As[(g.wm + ti * 32 + g.l31) * 64 + ((s * 2 + g.half) ^ sw) * 8];
#pragma unroll
  for (int tj = 0; tj < 2; ++tj)
#pragma unroll
    for (int s = 0; s < 4; ++s)
      bfm[tj][s] = *(const bf16x8*)&Bs[(g.wn + tj * 32 + g.l31) * 64 + ((s * 2 + g.half) ^ sw) * 8];

#pragma unroll
  for (int s = 0; s < 4; ++s)
#pragma unroll
    for (int ti = 0; ti < 2; ++ti)
#pragma unroll
      for (int tj = 0; tj < 2; ++tj)
        acc[ti][tj] = __builtin_amdgcn_mfma_f32_32x32x16_bf16(
            af[ti][s], bfm[tj][s], acc[ti][tj], 0, 0, 0);
}

// one sync per K-tile: own stages landed (vmcnt) + own ds_reads done (lgkm,
// pins reads against MFMA sinking) + cross-wave visibility (barrier).
__device__ __forceinline__ void sync_tile() {
  asm volatile("s_waitcnt vmcnt(0) lgkmcnt(0)" ::: "memory");
  __builtin_amdgcn_s_barrier();
}

// 2-phase double-buffered K-loop: stage(t+1) issued BEFORE compute(t) so the
// global_load_lds fly under the whole compute phase; single sync per tile.
__device__ __forceinline__ void gemm_kloop(const GemmCore& g, int K,
                                           bf16* As0, bf16* Bs0,
                                           bf16* As1, bf16* Bs1,
                                           f32x16 acc[2][2]) {
  stage_tile(g, 0, As0, Bs0);
  sync_tile();
  const int nt = K >> 6;            // 16 or 32 — always even here
#pragma unroll 1
  for (int t2 = 0; t2 < nt / 2 - 1; ++t2) {
    stage_tile(g, (2 * t2 + 1) * 64, As1, Bs1);
    compute_tile(g, As0, Bs0, acc);
    sync_tile();
    stage_tile(g, (2 * t2 + 2) * 64, As0, Bs0);
    compute_tile(g, As1, Bs1, acc);
    sync_tile();
  }
  stage_tile(g, (nt - 1) * 64, As1, Bs1);
  compute_tile(g, As0, Bs0, acc);
  sync_tile();
  compute_tile(g, As1, Bs1, acc);
}

// ---------------------------------------------------------------------------
// Plain GEMMs. MODE 0: store bf16. MODE 2: store fp32 v/L[row] + bias[col].
// ---------------------------------------------------------------------------
template <int MODE>
__launch_bounds__(256)
__global__ void gemm_bt(const bf16* __restrict__ Aroot, const bf16* __restrict__ Broot,
                        void* __restrict__ Croot, const float* __restrict__ bias,
                        const float* __restrict__ Lroot,
                        int K, int lda, int ldb, int ldc,
                        long strideA, long strideB, long strideC) {
  const bf16* A  = Aroot + (long)blockIdx.z * strideA;
  const bf16* Bm = Broot + (long)blockIdx.z * strideB;
  __shared__ alignas(16) bf16 As0[128 * 64];
  __shared__ alignas(16) bf16 Bs0[128 * 64];
  __shared__ alignas(16) bf16 As1[128 * 64];
  __shared__ alignas(16) bf16 Bs1[128 * 64];

  const long rowA = (long)blockIdx.y * 128;
  const long rowB = (long)blockIdx.x * 128;
  GemmCore g = gemm_setup(A, Bm, lda, ldb, rowA, rowB);

  f32x16 acc[2][2] = {};
  gemm_kloop(g, K, As0, Bs0, As1, Bs1, acc);

  if constexpr (MODE == 0) {
    bf16* C = (bf16*)Croot + (long)blockIdx.z * strideC;
#pragma unroll
    for (int ti = 0; ti < 2; ++ti)
#pragma unroll
      for (int tj = 0; tj < 2; ++tj) {
        const long col = rowB + g.wn + tj * 32 + g.l31;
#pragma unroll
        for (int r = 0; r < 16; ++r) {
          const long row = rowA + g.wm + ti * 32 + (r & 3) + 8 * (r >> 2) + 4 * g.half;
          C[row * (long)ldc + col] = (bf16)acc[ti][tj][r];
        }
      }
  } else {
    float* C = (float*)Croot + (long)blockIdx.z * strideC;
    const float* L = Lroot + (long)blockIdx.z * NTOK;
#pragma unroll
    for (int ti = 0; ti < 2; ++ti) {
#pragma unroll
      for (int r = 0; r < 16; ++r) {
        const long row = rowA + g.wm + ti * 32 + (r & 3) + 8 * (r >> 2) + 4 * g.half;
        const float inv = 1.0f / L[row];
#pragma unroll
        for (int tj = 0; tj < 2; ++tj) {
          const long col = rowB + g.wn + tj * 32 + g.l31;
          C[row * (long)ldc + col] = acc[ti][tj][r] * inv + bias[col];
        }
      }
    }
  }
}

// ---------------------------------------------------------------------------
// Fused dispatch: z<4 -> E_b = exp(Q_b@K_b^T/8) + row-sum L (batch z);
//                 z>=4 -> V''_b = Wout @ V_b^T (batch z-4; blockIdx.y>=8 idle).
// ---------------------------------------------------------------------------
__launch_bounds__(256)
__global__ void gemm_sv(const bf16* __restrict__ QKV, const bf16* __restrict__ Wout,
                        bf16* __restrict__ E, bf16* __restrict__ Vpp,
                        float* __restrict__ Lroot) {
  __shared__ alignas(16) bf16 As0[128 * 64];
  __shared__ alignas(16) bf16 Bs0[128 * 64];
  __shared__ alignas(16) bf16 As1[128 * 64];
  __shared__ alignas(16) bf16 Bs1[128 * 64];

  const int z = blockIdx.z;
  if (z < 4) {
    // ---- E-GEMM: A=Q, B=K rows of QKV batch z ----
    const bf16* A  = QKV + (long)z * NTOK * QKVC;
    const bf16* Bm = A + DIM;
    const long rowA = (long)blockIdx.y * 128;
    const long rowB = (long)blockIdx.x * 128;
    GemmCore g = gemm_setup(A, Bm, QKVC, QKVC, rowA, rowB);
    f32x16 acc[2][2] = {};
    gemm_kloop(g, DIM, As0, Bs0, As1, Bs1, acc);

    bf16* C = E + (long)z * NTOK * NTOK;
    float* L = Lroot + (long)z * NTOK;
#pragma unroll
    for (int ti = 0; ti < 2; ++ti) {
#pragma unroll
      for (int r = 0; r < 16; ++r) {
        const long row = rowA + g.wm + ti * 32 + (r & 3) + 8 * (r >> 2) + 4 * g.half;
        float psum = 0.f;
#pragma unroll
        for (int tj = 0; tj < 2; ++tj) {
          const long col = rowB + g.wn + tj * 32 + g.l31;
          float e = __expf(acc[ti][tj][r] * 0.125f);
          bf16 eb = (bf16)e;
          C[row * (long)NTOK + col] = eb;
          psum += (float)eb;   // sum what downstream consumes
        }
#pragma unroll
        for (int off = 16; off >= 1; off >>= 1) psum += __shfl_xor(psum, off, 64);
        if (g.l31 == 0) atomicAdd(&L[row], psum);
      }
    }
  } else {
    if (blockIdx.y >= 8) return;   // V'' output is 1024 rows = 8 row-tiles
    // ---- V''-GEMM: A=Wout (1024x1024), B=V rows of QKV batch z-4 ----
    const int b = z - 4;
    const bf16* Bm = QKV + (long)b * NTOK * QKVC + 2 * DIM;
    const long rowA = (long)blockIdx.y * 128;
    const long rowB = (long)blockIdx.x * 128;
    GemmCore g = gemm_setup(Wout, Bm, DIM, QKVC, rowA, rowB);
    f32x16 acc[2][2] = {};
    gemm_kloop(g, DIM, As0, Bs0, As1, Bs1, acc);

    bf16* C = Vpp + (long)b * DIM * NTOK;
#pragma unroll
    for (int ti = 0; ti < 2; ++ti)
#pragma unroll
      for (int tj = 0; tj < 2; ++tj) {
        const long col = rowB + g.wn + tj * 32 + g.l31;
#pragma unroll
        for (int r = 0; r < 16; ++r) {
          const long row = rowA + g.wm + ti * 32 + (r & 3) + 8 * (r >> 2) + 4 * g.half;
          C[row * (long)NTOK + col] = (bf16)acc[ti][tj][r];
        }
      }
  }
}

// ---------------------------------------------------------------------------
extern "C" void kernel_launch(void* const* d_in, const int* in_sizes, int n_in,
                              void* d_out, int out_size, void* d_ws, size_t ws_size,
                              hipStream_t stream) {
  const float* x      = (const float*)d_in[0];   // (4,2048,1024)
  const float* w_qkv  = (const float*)d_in[1];   // (3072,1024)
  const float* w_out  = (const float*)d_in[2];   // (1024,1024)
  const float* b_out  = (const float*)d_in[3];   // (1024,)
  float* out = (float*)d_out;                    // (4,2048,1024) fp32

  // workspace layout (bytes) — total ~120 MiB
  char* w = (char*)d_ws;
  bf16*  Xbf   = (bf16*)(w);                          // 8192*1024*2   = 16 MiB
  bf16*  Wqkvb = (bf16*)(w + 16777216);               // 3072*1024*2   =  6 MiB
  bf16*  Woutb = (bf16*)(w + 23068672);               // 1024*1024*2   =  2 MiB
  bf16*  QKV   = (bf16*)(w + 25165824);               // 8192*3072*2   = 48 MiB
  bf16*  E     = (bf16*)(w + 75497472);               // 4*2048*2048*2 = 32 MiB
  bf16*  Vpp   = (bf16*)(w + 109051904);              // 4*1024*2048*2 = 16 MiB
  float* L     = (float*)(w + 125829120);             // 4*2048*4      = 32 KiB

  // 1) one prep dispatch: converts + L zero
  {
    const int n4 = MROWS * DIM / 4 + QKVC * DIM / 4 + DIM * DIM / 4 + BATCH * NTOK / 4;
    prep<<<(n4 + 255) / 256, 256, 0, stream>>>(x, w_qkv, w_out, Xbf, Wqkvb, Woutb, L);
  }

  // 2) QKV = X @ Wqkv^T -> bf16 (8192 x 3072)
  gemm_bt<0><<<dim3(QKVC / 128, MROWS / 128, 1), 256, 0, stream>>>(
      Xbf, Wqkvb, QKV, nullptr, nullptr, DIM, DIM, DIM, QKVC, 0, 0, 0);

  // 3) fused: E_b = exp(Q_b@K_b^T/8) + L row-sums  AND  V''_b = Wout @ V_b^T
  gemm_sv<<<dim3(NTOK / 128, NTOK / 128, 2 * BATCH), 256, 0, stream>>>(
      QKV, Woutb, E, Vpp, L);

  // 4) out_b = (E_b @ V''_b^T) / L + b_out -> fp32 (2048 x 1024 per batch)
  gemm_bt<2><<<dim3(DIM / 128, NTOK / 128, BATCH), 256, 0, stream>>>(
      E, Vpp, out, b_out, L, NTOK, NTOK, NTOK, DIM,
      (long)NTOK * NTOK, (long)DIM * NTOK, (long)NTOK * DIM);
}